// Round 3
// baseline (692.705 us; speedup 1.0000x reference)
//
#include <hip/hip_runtime.h>
#include <climits>

#define N_MASKS 64
#define H 1024
#define W 1024
#define ROWS_PER_BLOCK 8
#define BLOCKS_PER_MASK (H / ROWS_PER_BLOCK)  // 128
#define THREADS 256

// Harness poisons d_ws to 0xAA bytes before EVERY launch (stated contract).
#define POISON ((int)0xAAAAAAAAu)  // -1431655766

// ws layout: per mask, 6 slots spaced 64 B apart (own cache line each):
//   +0   : atomicMax( cmax )            real values in [-1, 1023]  > POISON always
//   +16  : atomicMax( rmax )
//   +32  : atomicMax( -cmin )           real values in [-1023, 0]; empty -> INT_MIN (no-op)
//   +48  : atomicMax( -rmin )
//   +64  : atomicAdd( cnt )             final = POISON + total_count
//   +80  : atomicAdd( 1 )   done ctr    last block sees old == POISON + 127
#define MASK_STRIDE 96  // ints (384 B per mask)

__device__ __forceinline__ int imin(int a, int b) { return a < b ? a : b; }
__device__ __forceinline__ int imax(int a, int b) { return a > b ? a : b; }

__global__ __launch_bounds__(THREADS) void fastsam_fused(
    const float* __restrict__ masks, int* __restrict__ ws,
    float* __restrict__ out) {
    const int mask = blockIdx.y;
    const int bx = blockIdx.x;
    const int r0 = bx * ROWS_PER_BLOCK;
    const int t = threadIdx.x;

    const float4* base = (const float4*)(masks + (size_t)mask * H * W);
    const int col = t * 4;  // thread t covers cols [4t, 4t+3] of every row

    int cmin = INT_MAX, rmin = INT_MAX, cmax = -1, rmax = -1, cnt = 0;

#pragma unroll
    for (int i = 0; i < ROWS_PER_BLOCK; ++i) {
        const int row = r0 + i;
        float4 v = base[row * (W / 4) + t];
        bool a0 = (v.x == 1.0f);
        bool a1 = (v.y == 1.0f);
        bool a2 = (v.z == 1.0f);
        bool a3 = (v.w == 1.0f);
        cnt += (int)a0 + (int)a1 + (int)a2 + (int)a3;
        if (a0 | a1 | a2 | a3) {
            rmin = imin(rmin, row);
            rmax = imax(rmax, row);
            int lo = a0 ? col : (a1 ? col + 1 : (a2 ? col + 2 : col + 3));
            int hi = a3 ? col + 3 : (a2 ? col + 2 : (a1 ? col + 1 : col));
            cmin = imin(cmin, lo);
            cmax = imax(cmax, hi);
        }
    }

    // wave-64 butterfly reduce
#pragma unroll
    for (int off = 32; off > 0; off >>= 1) {
        cmin = imin(cmin, __shfl_down(cmin, off));
        rmin = imin(rmin, __shfl_down(rmin, off));
        cmax = imax(cmax, __shfl_down(cmax, off));
        rmax = imax(rmax, __shfl_down(rmax, off));
        cnt += __shfl_down(cnt, off);
    }

    __shared__ int s[4][5];
    const int wave = t >> 6;
    const int lane = t & 63;
    if (lane == 0) {
        s[wave][0] = cmin;
        s[wave][1] = rmin;
        s[wave][2] = cmax;
        s[wave][3] = rmax;
        s[wave][4] = cnt;
    }
    __syncthreads();
    if (t == 0) {
#pragma unroll
        for (int wv = 1; wv < 4; ++wv) {
            cmin = imin(cmin, s[wv][0]);
            rmin = imin(rmin, s[wv][1]);
            cmax = imax(cmax, s[wv][2]);
            rmax = imax(rmax, s[wv][3]);
            cnt += s[wv][4];
        }

        int* slots = ws + (size_t)mask * MASK_STRIDE;
        atomicMax(slots + 0, cmax);                              // cmax
        atomicMax(slots + 16, rmax);                             // rmax
        atomicMax(slots + 32, cmin == INT_MAX ? INT_MIN : -cmin);  // -cmin
        atomicMax(slots + 48, rmin == INT_MAX ? INT_MIN : -rmin);  // -rmin
        atomicAdd(slots + 64, cnt);                              // count (biased by POISON)
        __threadfence();  // data atomics visible before done-counter bump

        int old = atomicAdd(slots + 80, 1);
        if (old == POISON + (BLOCKS_PER_MASK - 1)) {
            // Last block for this mask: read accumulators via RMW (coherent),
            // decode, apply area test, write bbox.
            int fcmax = atomicMax(slots + 0, INT_MIN);
            int frmax = atomicMax(slots + 16, INT_MIN);
            int fcmin = -atomicMax(slots + 32, INT_MIN);
            int frmin = -atomicMax(slots + 48, INT_MIN);
            int total = atomicAdd(slots + 64, 0) - POISON;
            // area_thresh = (1024/32)*(1024/32) = 1024; binary mask => sum == count
            bool keep = total > 1024;
            out[mask * 4 + 0] = keep ? (float)fcmin : 0.0f;  // x1
            out[mask * 4 + 1] = keep ? (float)frmin : 0.0f;  // y1
            out[mask * 4 + 2] = keep ? (float)fcmax : 0.0f;  // x2
            out[mask * 4 + 3] = keep ? (float)frmax : 0.0f;  // y2
        }
    }
}

extern "C" void kernel_launch(void* const* d_in, const int* in_sizes, int n_in,
                              void* d_out, int out_size, void* d_ws, size_t ws_size,
                              hipStream_t stream) {
    const float* masks = (const float*)d_in[0];
    float* out = (float*)d_out;
    int* ws = (int*)d_ws;

    dim3 grid(BLOCKS_PER_MASK, N_MASKS);  // 128 x 64 = 8192 blocks, one dispatch
    fastsam_fused<<<grid, THREADS, 0, stream>>>(masks, ws, out);
}

// Round 4
// 353.475 us; speedup vs baseline: 1.9597x; 1.9597x over previous
//
#include <hip/hip_runtime.h>
#include <climits>

#define N_MASKS 64
#define H 1024
#define W 1024
#define ROWS_PER_BLOCK 8
#define BLOCKS_PER_MASK (H / ROWS_PER_BLOCK)  // 128
#define THREADS 256

// Harness poisons d_ws to 0xAA bytes before EVERY launch (stated contract,
// validated by R3 passing with this encoding).
#define POISON ((int)0xAAAAAAAAu)  // -1431655766

// ws layout: per mask, 6 slots spaced 64 B apart (own cache line each):
//   +0   : atomicMax( cmax )             real values in [-1, 1023]  > POISON always
//   +16  : atomicMax( rmax )
//   +32  : atomicMax( -cmin )            real values in [-1023, 0]; empty -> INT_MIN (no-op)
//   +48  : atomicMax( -rmin )
//   +64  : atomicAdd( cnt )              final = POISON + total_count
//   +80  : atomicAdd( 1 )  done counter  last block sees old == POISON + 127
#define MASK_STRIDE 96  // ints (384 B per mask)

__device__ __forceinline__ int imin(int a, int b) { return a < b ? a : b; }
__device__ __forceinline__ int imax(int a, int b) { return a > b ? a : b; }

__global__ __launch_bounds__(THREADS) void fastsam_fused(
    const float* __restrict__ masks, int* __restrict__ ws,
    float* __restrict__ out) {
    const int mask = blockIdx.y;
    const int bx = blockIdx.x;
    const int r0 = bx * ROWS_PER_BLOCK;
    const int t = threadIdx.x;

    const float4* base = (const float4*)(masks + (size_t)mask * H * W);
    const int col = t * 4;  // thread t covers cols [4t, 4t+3] of every row

    int cmin = INT_MAX, rmin = INT_MAX, cmax = -1, rmax = -1, cnt = 0;

#pragma unroll
    for (int i = 0; i < ROWS_PER_BLOCK; ++i) {
        const int row = r0 + i;
        float4 v = base[row * (W / 4) + t];
        bool a0 = (v.x == 1.0f);
        bool a1 = (v.y == 1.0f);
        bool a2 = (v.z == 1.0f);
        bool a3 = (v.w == 1.0f);
        cnt += (int)a0 + (int)a1 + (int)a2 + (int)a3;
        if (a0 | a1 | a2 | a3) {
            rmin = imin(rmin, row);
            rmax = imax(rmax, row);
            int lo = a0 ? col : (a1 ? col + 1 : (a2 ? col + 2 : col + 3));
            int hi = a3 ? col + 3 : (a2 ? col + 2 : (a1 ? col + 1 : col));
            cmin = imin(cmin, lo);
            cmax = imax(cmax, hi);
        }
    }

    // wave-64 butterfly reduce
#pragma unroll
    for (int off = 32; off > 0; off >>= 1) {
        cmin = imin(cmin, __shfl_down(cmin, off));
        rmin = imin(rmin, __shfl_down(rmin, off));
        cmax = imax(cmax, __shfl_down(cmax, off));
        rmax = imax(rmax, __shfl_down(rmax, off));
        cnt += __shfl_down(cnt, off);
    }

    __shared__ int s[4][5];
    const int wave = t >> 6;
    const int lane = t & 63;
    if (lane == 0) {
        s[wave][0] = cmin;
        s[wave][1] = rmin;
        s[wave][2] = cmax;
        s[wave][3] = rmax;
        s[wave][4] = cnt;
    }
    __syncthreads();
    if (t == 0) {
#pragma unroll
        for (int wv = 1; wv < 4; ++wv) {
            cmin = imin(cmin, s[wv][0]);
            rmin = imin(rmin, s[wv][1]);
            cmax = imax(cmax, s[wv][2]);
            rmax = imax(rmax, s[wv][3]);
            cnt += s[wv][4];
        }

        int* slots = ws + (size_t)mask * MASK_STRIDE;
        // RETURNING atomics: the old value arriving proves the op executed at
        // the coherence point. No fence needed (no ordinary global stores in
        // flight) — avoids the buffer_wbl2 L2-writeback storm that made R3
        // take 443 us.
        int o0 = atomicMax(slots + 0, cmax);                                 // cmax
        int o1 = atomicMax(slots + 16, rmax);                                // rmax
        int o2 = atomicMax(slots + 32, cmin == INT_MAX ? INT_MIN : -cmin);   // -cmin
        int o3 = atomicMax(slots + 48, rmin == INT_MAX ? INT_MIN : -rmin);   // -rmin
        int o4 = atomicAdd(slots + 64, cnt);                                 // count (POISON-biased)

        // Launder the results into a value the compiler can't fold away, so
        // the done-counter add has a true data dependency on all 5 atomics.
        int mix = o0 ^ o1 ^ o2 ^ o3 ^ o4;
        int zero;
        asm volatile("v_and_b32 %0, 0, %1" : "=v"(zero) : "v"(mix));

        int old = atomicAdd(slots + 80, 1 + zero);  // zero == 0 always
        if (old == POISON + (BLOCKS_PER_MASK - 1)) {
            // Last block for this mask: read accumulators via returning RMWs
            // (execute at the coherence point), decode, area-test, write bbox.
            int fcmax = atomicMax(slots + 0, INT_MIN);
            int frmax = atomicMax(slots + 16, INT_MIN);
            int fcmin = -atomicMax(slots + 32, INT_MIN);
            int frmin = -atomicMax(slots + 48, INT_MIN);
            int total = atomicAdd(slots + 64, 0) - POISON;
            // area_thresh = (1024/32)*(1024/32) = 1024; binary mask => sum == count
            bool keep = total > 1024;
            out[mask * 4 + 0] = keep ? (float)fcmin : 0.0f;  // x1
            out[mask * 4 + 1] = keep ? (float)frmin : 0.0f;  // y1
            out[mask * 4 + 2] = keep ? (float)fcmax : 0.0f;  // x2
            out[mask * 4 + 3] = keep ? (float)frmax : 0.0f;  // y2
        }
    }
}

extern "C" void kernel_launch(void* const* d_in, const int* in_sizes, int n_in,
                              void* d_out, int out_size, void* d_ws, size_t ws_size,
                              hipStream_t stream) {
    const float* masks = (const float*)d_in[0];
    float* out = (float*)d_out;
    int* ws = (int*)d_ws;

    dim3 grid(BLOCKS_PER_MASK, N_MASKS);  // 128 x 64 = 8192 blocks, one dispatch
    fastsam_fused<<<grid, THREADS, 0, stream>>>(masks, ws, out);
}

// Round 5
// 352.129 us; speedup vs baseline: 1.9672x; 1.0038x over previous
//
#include <hip/hip_runtime.h>
#include <climits>

#define N_MASKS 64
#define H 1024
#define W 1024
#define ROWS_PER_BLOCK 8
#define BLOCKS_PER_MASK (H / ROWS_PER_BLOCK)  // 128
#define THREADS 256

// Harness poisons d_ws to 0xAA bytes before EVERY launch (stated contract,
// validated by R3/R4 passing with this encoding).
#define POISON ((int)0xAAAAAAAAu)  // -1431655766

// ws layout: per mask, 6 slots spaced 64 B apart (own cache line each):
//   +0   : atomicMax( cmax )             real values in [-1, 1023]  > POISON always
//   +16  : atomicMax( rmax )
//   +32  : atomicMax( -cmin )            real values in [-1023, 0]; empty -> INT_MIN (no-op)
//   +48  : atomicMax( -rmin )
//   +64  : atomicAdd( cnt )              final = POISON + total_count
//   +80  : atomicAdd( 1 )  done counter  last block sees old == POISON + 127
#define MASK_STRIDE 96  // ints (384 B per mask)

__device__ __forceinline__ int imin(int a, int b) { return a < b ? a : b; }
__device__ __forceinline__ int imax(int a, int b) { return a > b ? a : b; }

__global__ __launch_bounds__(THREADS) void fastsam_fused(
    const float* __restrict__ masks, int* __restrict__ ws,
    float* __restrict__ out) {
    const int mask = blockIdx.y;
    const int bx = blockIdx.x;
    const int r0 = bx * ROWS_PER_BLOCK;
    const int t = threadIdx.x;

    const float4* base = (const float4*)(masks + (size_t)mask * H * W);
    const int col = t * 4;  // thread t covers cols [4t, 4t+3] of every row

    // Batch ALL row loads first: 8 independent global_load_dwordx4 in flight
    // per thread (8 KB/wave outstanding) instead of load->use serialization.
    // R3's VGPR_Count=20 showed the compiler was NOT doing this on its own;
    // the kernel ran latency-bound at ~2.6 TB/s.
    float4 v[ROWS_PER_BLOCK];
#pragma unroll
    for (int i = 0; i < ROWS_PER_BLOCK; ++i) {
        v[i] = base[(size_t)(r0 + i) * (W / 4) + t];
    }

    int cmin = INT_MAX, rmin = INT_MAX, cmax = -1, rmax = -1, cnt = 0;

#pragma unroll
    for (int i = 0; i < ROWS_PER_BLOCK; ++i) {
        const int row = r0 + i;
        bool a0 = (v[i].x == 1.0f);
        bool a1 = (v[i].y == 1.0f);
        bool a2 = (v[i].z == 1.0f);
        bool a3 = (v[i].w == 1.0f);
        cnt += (int)a0 + (int)a1 + (int)a2 + (int)a3;
        if (a0 | a1 | a2 | a3) {
            rmin = imin(rmin, row);
            rmax = imax(rmax, row);
            int lo = a0 ? col : (a1 ? col + 1 : (a2 ? col + 2 : col + 3));
            int hi = a3 ? col + 3 : (a2 ? col + 2 : (a1 ? col + 1 : col));
            cmin = imin(cmin, lo);
            cmax = imax(cmax, hi);
        }
    }

    // wave-64 butterfly reduce
#pragma unroll
    for (int off = 32; off > 0; off >>= 1) {
        cmin = imin(cmin, __shfl_down(cmin, off));
        rmin = imin(rmin, __shfl_down(rmin, off));
        cmax = imax(cmax, __shfl_down(cmax, off));
        rmax = imax(rmax, __shfl_down(rmax, off));
        cnt += __shfl_down(cnt, off);
    }

    __shared__ int s[4][5];
    const int wave = t >> 6;
    const int lane = t & 63;
    if (lane == 0) {
        s[wave][0] = cmin;
        s[wave][1] = rmin;
        s[wave][2] = cmax;
        s[wave][3] = rmax;
        s[wave][4] = cnt;
    }
    __syncthreads();
    if (t == 0) {
#pragma unroll
        for (int wv = 1; wv < 4; ++wv) {
            cmin = imin(cmin, s[wv][0]);
            rmin = imin(rmin, s[wv][1]);
            cmax = imax(cmax, s[wv][2]);
            rmax = imax(rmax, s[wv][3]);
            cnt += s[wv][4];
        }

        int* slots = ws + (size_t)mask * MASK_STRIDE;
        // RETURNING atomics: the old value arriving proves the op executed at
        // the coherence point. No fence needed (no ordinary global stores in
        // flight) — avoids the buffer_wbl2 L2-writeback storm of R3.
        int o0 = atomicMax(slots + 0, cmax);                                 // cmax
        int o1 = atomicMax(slots + 16, rmax);                                // rmax
        int o2 = atomicMax(slots + 32, cmin == INT_MAX ? INT_MIN : -cmin);   // -cmin
        int o3 = atomicMax(slots + 48, rmin == INT_MAX ? INT_MIN : -rmin);   // -rmin
        int o4 = atomicAdd(slots + 64, cnt);                                 // count (POISON-biased)

        // Launder results so the done-counter add has a true data dependency
        // on all 5 atomics (ordering without a fence).
        int mix = o0 ^ o1 ^ o2 ^ o3 ^ o4;
        int zero;
        asm volatile("v_and_b32 %0, 0, %1" : "=v"(zero) : "v"(mix));

        int old = atomicAdd(slots + 80, 1 + zero);  // zero == 0 always
        if (old == POISON + (BLOCKS_PER_MASK - 1)) {
            // Last block for this mask: read accumulators via returning RMWs
            // (execute at the coherence point), decode, area-test, write bbox.
            int fcmax = atomicMax(slots + 0, INT_MIN);
            int frmax = atomicMax(slots + 16, INT_MIN);
            int fcmin = -atomicMax(slots + 32, INT_MIN);
            int frmin = -atomicMax(slots + 48, INT_MIN);
            int total = atomicAdd(slots + 64, 0) - POISON;
            // area_thresh = (1024/32)*(1024/32) = 1024; binary mask => sum == count
            bool keep = total > 1024;
            out[mask * 4 + 0] = keep ? (float)fcmin : 0.0f;  // x1
            out[mask * 4 + 1] = keep ? (float)frmin : 0.0f;  // y1
            out[mask * 4 + 2] = keep ? (float)fcmax : 0.0f;  // x2
            out[mask * 4 + 3] = keep ? (float)frmax : 0.0f;  // y2
        }
    }
}

extern "C" void kernel_launch(void* const* d_in, const int* in_sizes, int n_in,
                              void* d_out, int out_size, void* d_ws, size_t ws_size,
                              hipStream_t stream) {
    const float* masks = (const float*)d_in[0];
    float* out = (float*)d_out;
    int* ws = (int*)d_ws;

    dim3 grid(BLOCKS_PER_MASK, N_MASKS);  // 128 x 64 = 8192 blocks, one dispatch
    fastsam_fused<<<grid, THREADS, 0, stream>>>(masks, ws, out);
}